// Round 1
// baseline (744.719 us; speedup 1.0000x reference)
//
#include <hip/hip_runtime.h>
#include <hip/hip_cooperative_groups.h>

#define B_SZ 16
#define N_SZ 8192
#define D_SZ 384
#define KN_SZ 16
#define K_SZ 8
#define H_SZ 128
#define M_TOTAL (B_SZ * N_SZ)   // 131072 nodes
#define KSTEPS 12               // 384 / 32
#define MT64 (M_TOTAL / 64)     // 2048 64-row tiles
#define LDSA_STRIDE 400         // bf16 elems; 200 dw == 8 mod 32 -> conflict-free b128

typedef short short8 __attribute__((ext_vector_type(8)));
typedef short short4v __attribute__((ext_vector_type(4)));
typedef float floatx4 __attribute__((ext_vector_type(4)));

__device__ __forceinline__ unsigned short f2bf(float f) {
    unsigned u = __builtin_bit_cast(unsigned, f);
    u += 0x7FFFu + ((u >> 16) & 1u);   // round-to-nearest-even
    return (unsigned short)(u >> 16);
}
__device__ __forceinline__ float bf2f(unsigned short b) {
    unsigned u = ((unsigned)b) << 16;
    return __builtin_bit_cast(float, u);
}
// HW packed f32->bf16 (RNE), 2 elems / inst: D.lo = bf16(a), D.hi = bf16(b)
__device__ __forceinline__ unsigned pkbf(float a, float b) {
    unsigned r;
    asm("v_cvt_pk_bf16_f32 %0, %1, %2" : "=v"(r) : "v"(a), "v"(b));
    return r;
}

// ---------------------------------------------------------------------------
// PREP: blocks 0..383 build swizzled fused weights; block 384 zeroes norms;
// blocks 385..400 per-batch q contributions (+layer-1 biases), exact fp32.
// wswz: flat = ((ct*12+s)*64 + lane)*8 + j <-> B[k=s*32+(lane>>4)*8+j][n=ct*16+(lane&15)]
// ---------------------------------------------------------------------------
__global__ void prep_kernel(const float* __restrict__ q_embs,
                            const float* __restrict__ coin_w1,
                            const float* __restrict__ coin_b1,
                            const float* __restrict__ path_w1,
                            const float* __restrict__ path_b1,
                            unsigned short* __restrict__ wswz,
                            float* __restrict__ qcoin, float* __restrict__ qpath,
                            float* __restrict__ norms) {
    int blk = blockIdx.x;
    int t = threadIdx.x;
    if (blk < 384) {
        int f = blk * 256 + t;                   // 98304 total
        int j  = f & 7;
        int l  = (f >> 3) & 63;
        int ss = (f >> 9) % KSTEPS;
        int ct = f / (KSTEPS * 512);
        int k = ss * 32 + ((l >> 4) << 3) + j;
        int n = ct * 16 + (l & 15);
        float v = (n < H_SZ) ? coin_w1[k * H_SZ + n]
                             : path_w1[k * H_SZ + (n - H_SZ)];
        wswz[f] = f2bf(v);
    } else if (blk == 384) {
        if (t < B_SZ) norms[t] = 0.f;
    } else {
        int b = blk - 385;
        const float* q = q_embs + b * D_SZ;
        if (t < H_SZ) {
            float acc = coin_b1[t];
            for (int d = 0; d < D_SZ; d++)
                acc += q[d] * coin_w1[(D_SZ + d) * H_SZ + t];
            qcoin[b * H_SZ + t] = acc;
        } else if (t < 2 * H_SZ) {
            int h = t - H_SZ;
            float acc = path_b1[h];
            for (int d = 0; d < D_SZ; d++)
                acc += q[d] * path_w1[(D_SZ + K_SZ + d) * H_SZ + h];
            qpath[b * H_SZ + h] = acc;
        }
    }
}

// ---------------------------------------------------------------------------
// GEMM v5: one 64-row tile per block, staged LDS, cvt_pk bf16 conversion.
// Fused epilogue: path-h stored blocked to global (bf16); coin-h never leaves
// the block — relu(h+qcoin) -> LDS (reusing the staging buffer) -> amps + z0.
// ---------------------------------------------------------------------------
__global__ __launch_bounds__(256)
void gemm_fused(const float* __restrict__ sent,
                const unsigned short* __restrict__ wswz,
                const float* __restrict__ qcoin,
                const float* __restrict__ coin_w2,
                const float* __restrict__ coin_b2,
                unsigned short* __restrict__ hpathB,
                float* __restrict__ amps,
                float* __restrict__ z0) {
    __shared__ __align__(16) short als[64 * LDSA_STRIDE];   // 51200 B -> 3 blocks/CU
    const int tid = threadIdx.x;
    const int wave = tid >> 6, lane = tid & 63;
    const int m_lane = lane & 15, quad = lane >> 4;
    const int mt = blockIdx.x;                   // 2048 blocks, one tile each
    const int b = mt >> 7;                       // batch (8192 rows / batch)

    // ---- stage A: 64 rows x 384 fp32 -> bf16 LDS via v_cvt_pk_bf16_f32 ----
    const float* abase = sent + (size_t)mt * 64 * D_SZ;
#pragma unroll
    for (int g = 0; g < 3; g++) {
        float4 v[8];
#pragma unroll
        for (int u = 0; u < 8; u++)
            v[u] = *(const float4*)(abase + (size_t)((g * 8 + u) * 256 + tid) * 4);
#pragma unroll
        for (int u = 0; u < 8; u++) {
            int e4 = (g * 8 + u) * 256 + tid;
            int row = e4 / 96;                   // 96 float4 per row
            int c4  = e4 - row * 96;
            int2 p;
            p.x = (int)pkbf(v[u].x, v[u].y);
            p.y = (int)pkbf(v[u].z, v[u].w);
            *(int2*)&als[row * LDSA_STRIDE + c4 * 4] = p;
        }
    }
    __syncthreads();

    // ---- K-loop ----
    const unsigned short* wbase = wswz + (size_t)wave * 4 * KSTEPS * 512 + lane * 8;
    floatx4 acc[4][4];
#pragma unroll
    for (int rt = 0; rt < 4; rt++)
#pragma unroll
        for (int c = 0; c < 4; c++) acc[rt][c] = (floatx4){0.f, 0.f, 0.f, 0.f};

#pragma unroll
    for (int s = 0; s < KSTEPS; s++) {
        short8 bf[4];
#pragma unroll
        for (int c = 0; c < 4; c++)
            bf[c] = *(const short8*)(wbase + (size_t)(c * KSTEPS + s) * 512);
        short8 af[4];
#pragma unroll
        for (int rt = 0; rt < 4; rt++)
            af[rt] = *(const short8*)&als[(rt * 16 + m_lane) * LDSA_STRIDE + s * 32 + quad * 8];
#pragma unroll
        for (int rt = 0; rt < 4; rt++)
#pragma unroll
            for (int c = 0; c < 4; c++)
                acc[rt][c] = __builtin_amdgcn_mfma_f32_16x16x32_bf16(af[rt], bf[c], acc[rt][c], 0, 0, 0);
    }

    // ---- epilogue A: path waves store blocked bf16 h to global ----
    if (wave >= 2) {
        const int colw = (wave & 1) * 64;
#pragma unroll
        for (int rt = 0; rt < 4; rt++) {
            int mt16 = mt * 4 + rt;
#pragma unroll
            for (int c = 0; c < 4; c++) {
                int col = colw + c * 16 + m_lane;
                int2 p;
                p.x = (int)pkbf(acc[rt][c][0], acc[rt][c][1]);
                p.y = (int)pkbf(acc[rt][c][2], acc[rt][c][3]);
                *(int2*)(hpathB + (size_t)mt16 * 2048 + col * 16 + quad * 4) = p;
            }
        }
    }
    __syncthreads();                             // als K-loop reads all done

    // ---- epilogue B: coin waves -> relu(h + qcoin) into LDS (f32) ----
    float* hs  = (float*)als;                    // 64 x 132 f32 = 33792 B
    float* w2s = hs + 64 * 132;                  // 1024 f32 (ends 37888 <= 51200)
    if (wave < 2) {
        const int colw = wave * 64;
        float qc[4];
#pragma unroll
        for (int c = 0; c < 4; c++)
            qc[c] = qcoin[b * H_SZ + colw + c * 16 + m_lane];
#pragma unroll
        for (int rt = 0; rt < 4; rt++)
#pragma unroll
            for (int c = 0; c < 4; c++) {
                int colj = colw + c * 16 + m_lane;
#pragma unroll
                for (int j = 0; j < 4; j++) {
                    int row = rt * 16 + quad * 4 + j;
                    float hv = acc[rt][c][j] + qc[c];
                    hs[row * 132 + colj] = hv > 0.f ? hv : 0.f;
                }
            }
    }
    for (int i = tid; i < H_SZ * K_SZ; i += 256) w2s[i] = coin_w2[i];
    __syncthreads();

    // ---- epilogue C: amps[m][k] = hs_row @ w2 + b2 ; z0 = amps / 256 ----
    {
        const int r = tid >> 2;                  // 0..63 row in tile
        const int kk = (tid & 3) * 2;            // k pair
        float a0 = coin_b2[kk], a1 = coin_b2[kk + 1];
#pragma unroll 8
        for (int c = 0; c < H_SZ; c++) {
            float hv = hs[r * 132 + c];
            float2 w = *(const float2*)&w2s[c * 8 + kk];
            a0 += hv * w.x; a1 += hv * w.y;
        }
        const size_t m = (size_t)mt * 64 + r;
        const float c0 = 1.0f / 256.0f;          // 1/sqrt(N*K)
        *(float2*)(amps + m * 8 + kk) = make_float2(a0, a1);
        *(float2*)(z0   + m * 8 + kk) = make_float2(a0 * c0, a1 * c0);
    }
}

// ---------------------------------------------------------------------------
// walk phase body (un-normalized; intermediate norms cancel algebraically)
// ---------------------------------------------------------------------------
__device__ __forceinline__ void walk_phase(const float* __restrict__ z,
                                           float* __restrict__ outz,
                                           const int* __restrict__ neighbors,
                                           const float* __restrict__ amps,
                                           float* __restrict__ norms,
                                           float* blocksum, int last) {
    const int g = blockIdx.x * 256 + threadIdx.x;    // 262144 threads exactly
    const int m = g >> 1, half = g & 1;
    const int b = m >> 13;
    const size_t nbase = (size_t)b << 13;
    const int off = half * 4;

    float4 v = *(const float4*)(z + (size_t)m * 8 + off);
    int nbr[KN_SZ];
    const int4* nb4 = (const int4*)(neighbors + (size_t)m * KN_SZ);
#pragma unroll
    for (int i = 0; i < 4; i++) *(int4*)&nbr[i * 4] = nb4[i];
#pragma unroll
    for (int i = 0; i < KN_SZ; i++) {
        int nn = nbr[i];
        if (nn >= 0 && nn < N_SZ) {
            float4 gv = *(const float4*)(z + (nbase + nn) * 8 + off);
            v.x += gv.x; v.y += gv.y; v.z += gv.z; v.w += gv.w;
        }
    }
    if (!last) {
        float4 a = *(const float4*)(amps + (size_t)m * 8 + off);
        v.x *= a.x; v.y *= a.y; v.z *= a.z; v.w *= a.w;
        *(float4*)(outz + (size_t)m * 8 + off) = v;
    } else {
        *(float4*)(outz + (size_t)m * 8 + off) = v;
        float ss = v.x * v.x + v.y * v.y + v.z * v.z + v.w * v.w;
#pragma unroll
        for (int o = 32; o > 0; o >>= 1) ss += __shfl_down(ss, o);
        if (threadIdx.x == 0) *blocksum = 0.f;
        __syncthreads();
        if ((threadIdx.x & 63) == 0) atomicAdd(blocksum, ss);
        __syncthreads();
        if (threadIdx.x == 0) atomicAdd(&norms[b], *blocksum);
    }
}

// ---------------------------------------------------------------------------
// MEGA (cooperative, 1024 blocks x 256): walk1, walk2, walk3+norms, logits.
// logits: 2 threads per node split the h-loop (64 iters each), shfl combine.
// ---------------------------------------------------------------------------
__global__ __launch_bounds__(256, 4)
void mega_kernel(float* __restrict__ zA, float* __restrict__ zB,
                 const int* __restrict__ neighbors,
                 const float* __restrict__ amps,
                 float* __restrict__ norms,
                 const unsigned short* __restrict__ hpathB,
                 const float* __restrict__ qpath,
                 const float* __restrict__ path_w1,
                 const float* __restrict__ path_w2,
                 const float* __restrict__ path_b2,
                 float* __restrict__ out) {
    cooperative_groups::grid_group grid = cooperative_groups::this_grid();
    __shared__ float w1t[H_SZ * K_SZ];   // w1t[h*8+j] = path_w1[(384+j)*128 + h]
    __shared__ float w2sp[H_SZ];
    __shared__ float qps[H_SZ];
    __shared__ float blocksum;
    const int tid = threadIdx.x;
    const int mbase = blockIdx.x * 128;          // 128 nodes per block in logits
    const int b = mbase >> 13;                   // block-uniform batch

    // stage logits weights up-front (LDS free during walk phases)
    for (int i = tid; i < H_SZ * K_SZ; i += 256) {
        int h = i >> 3, j = i & 7;
        w1t[i] = path_w1[(D_SZ + j) * H_SZ + h];
    }
    if (tid < H_SZ) { w2sp[tid] = path_w2[tid]; qps[tid] = qpath[b * H_SZ + tid]; }

    walk_phase(zA, zB, neighbors, amps, norms, &blocksum, 0);
    grid.sync();
    walk_phase(zB, zA, neighbors, amps, norms, &blocksum, 0);
    grid.sync();
    walk_phase(zA, zB, neighbors, amps, norms, &blocksum, 1);
    grid.sync();                                 // norms complete + visible

    // ---- logits ----
    float ssq = norms[b];
    float inv = ssq > 0.f ? rsqrtf(ssq) : 1.0f;
    const int m = mbase + (tid >> 1);
    const int hh = tid & 1;                      // which half of h-range
    float st[K_SZ];
    {
        float4 s0 = *(const float4*)(zB + (size_t)m * 8);
        float4 s1 = *(const float4*)(zB + (size_t)m * 8 + 4);
        st[0] = s0.x * inv; st[1] = s0.y * inv; st[2] = s0.z * inv; st[3] = s0.w * inv;
        st[4] = s1.x * inv; st[5] = s1.y * inv; st[6] = s1.z * inv; st[7] = s1.w * inv;
    }
    const unsigned short* hb = hpathB + (size_t)(m >> 4) * 2048 + (m & 15);
    float acc = hh ? 0.f : path_b2[0];
    const int h0 = hh * 64;
    for (int h = h0; h < h0 + 64; h++) {
        float hv = bf2f(hb[h * 16]) + qps[h];
        float4 wa = *(const float4*)&w1t[h * 8];
        float4 wb = *(const float4*)&w1t[h * 8 + 4];
        hv += st[0]*wa.x + st[1]*wa.y + st[2]*wa.z + st[3]*wa.w
            + st[4]*wb.x + st[5]*wb.y + st[6]*wb.z + st[7]*wb.w;
        hv = hv > 0.f ? hv : 0.f;
        acc += hv * w2sp[h];
    }
    float other = __shfl_xor(acc, 1);
    if (!hh) out[m] = acc + other;
}

// ---------------------------------------------------------------------------
extern "C" void kernel_launch(void* const* d_in, const int* in_sizes, int n_in,
                              void* d_out, int out_size, void* d_ws, size_t ws_size,
                              hipStream_t stream) {
    const float* sent      = (const float*)d_in[0];
    const float* q_embs    = (const float*)d_in[1];
    const int*   neighbors = (const int*)d_in[2];
    const float* coin_w1   = (const float*)d_in[3];
    const float* coin_b1   = (const float*)d_in[4];
    const float* coin_w2   = (const float*)d_in[5];
    const float* coin_b2   = (const float*)d_in[6];
    const float* path_w1   = (const float*)d_in[7];
    const float* path_b1   = (const float*)d_in[8];
    const float* path_w2   = (const float*)d_in[9];
    const float* path_b2   = (const float*)d_in[10];
    float* out = (float*)d_out;

    char* ws = (char*)d_ws;
    unsigned short* wswz = (unsigned short*)ws;                   // 196608 B
    float* qcoin = (float*)(ws + 196608);                         // 8192 B
    float* qpath = (float*)(ws + 204800);                         // 8192 B
    float* norms = (float*)(ws + 212992);                         // 256 B
    unsigned short* hpathB = (unsigned short*)(ws + 213248);      // 33554432 B
    float* amps = (float*)(ws + 33767680);                        // 4 MB
    float* zA   = (float*)(ws + 37961984);                        // 4 MB
    float* zB   = (float*)(ws + 42156288);                        // 4 MB

    prep_kernel<<<401, 256, 0, stream>>>(q_embs, coin_w1, coin_b1, path_w1, path_b1,
                                         wswz, qcoin, qpath, norms);
    gemm_fused<<<MT64, 256, 0, stream>>>(sent, wswz, qcoin, coin_w2, coin_b2,
                                         hpathB, amps, zA);
    void* margs[] = { (void*)&zA, (void*)&zB, (void*)&neighbors, (void*)&amps,
                      (void*)&norms, (void*)&hpathB, (void*)&qpath,
                      (void*)&path_w1, (void*)&path_w2, (void*)&path_b2, (void*)&out };
    hipLaunchCooperativeKernel((void*)mega_kernel, dim3(1024), dim3(256),
                               margs, 0, stream);
}

// Round 2
// 406.875 us; speedup vs baseline: 1.8303x; 1.8303x over previous
//
#include <hip/hip_runtime.h>

#define B_SZ 16
#define N_SZ 8192
#define D_SZ 384
#define KN_SZ 16
#define K_SZ 8
#define H_SZ 128
#define M_TOTAL (B_SZ * N_SZ)   // 131072 nodes
#define KSTEPS 12               // 384 / 32
#define MT64 (M_TOTAL / 64)     // 2048 64-row tiles
#define LDSA_STRIDE 400         // bf16 elems; 200 dw == 8 mod 32 -> conflict-free b128

typedef short short8 __attribute__((ext_vector_type(8)));
typedef short short4v __attribute__((ext_vector_type(4)));
typedef float floatx4 __attribute__((ext_vector_type(4)));

__device__ __forceinline__ unsigned short f2bf(float f) {
    unsigned u = __builtin_bit_cast(unsigned, f);
    u += 0x7FFFu + ((u >> 16) & 1u);   // round-to-nearest-even
    return (unsigned short)(u >> 16);
}
__device__ __forceinline__ float bf2f(unsigned short b) {
    unsigned u = ((unsigned)b) << 16;
    return __builtin_bit_cast(float, u);
}
// HW packed f32->bf16 (RNE), 2 elems / inst: D.lo = bf16(a), D.hi = bf16(b)
__device__ __forceinline__ unsigned pkbf(float a, float b) {
    unsigned r;
    asm("v_cvt_pk_bf16_f32 %0, %1, %2" : "=v"(r) : "v"(a), "v"(b));
    return r;
}

// ---------------------------------------------------------------------------
// PREP: blocks 0..383 build swizzled fused weights; block 384 zeroes norms;
// blocks 385..400 per-batch q contributions (+layer-1 biases), exact fp32.
// wswz: flat = ((ct*12+s)*64 + lane)*8 + j <-> B[k=s*32+(lane>>4)*8+j][n=ct*16+(lane&15)]
// ---------------------------------------------------------------------------
__global__ void prep_kernel(const float* __restrict__ q_embs,
                            const float* __restrict__ coin_w1,
                            const float* __restrict__ coin_b1,
                            const float* __restrict__ path_w1,
                            const float* __restrict__ path_b1,
                            unsigned short* __restrict__ wswz,
                            float* __restrict__ qcoin, float* __restrict__ qpath,
                            float* __restrict__ norms) {
    int blk = blockIdx.x;
    int t = threadIdx.x;
    if (blk < 384) {
        int f = blk * 256 + t;                   // 98304 total
        int j  = f & 7;
        int l  = (f >> 3) & 63;
        int ss = (f >> 9) % KSTEPS;
        int ct = f / (KSTEPS * 512);
        int k = ss * 32 + ((l >> 4) << 3) + j;
        int n = ct * 16 + (l & 15);
        float v = (n < H_SZ) ? coin_w1[k * H_SZ + n]
                             : path_w1[k * H_SZ + (n - H_SZ)];
        wswz[f] = f2bf(v);
    } else if (blk == 384) {
        if (t < B_SZ) norms[t] = 0.f;
    } else {
        int b = blk - 385;
        const float* q = q_embs + b * D_SZ;
        if (t < H_SZ) {
            float acc = coin_b1[t];
            for (int d = 0; d < D_SZ; d++)
                acc += q[d] * coin_w1[(D_SZ + d) * H_SZ + t];
            qcoin[b * H_SZ + t] = acc;
        } else if (t < 2 * H_SZ) {
            int h = t - H_SZ;
            float acc = path_b1[h];
            for (int d = 0; d < D_SZ; d++)
                acc += q[d] * path_w1[(D_SZ + K_SZ + d) * H_SZ + h];
            qpath[b * H_SZ + h] = acc;
        }
    }
}

// ---------------------------------------------------------------------------
// GEMM v5: one 64-row tile per block, staged LDS, cvt_pk bf16 conversion.
// Fused epilogue: path-h stored blocked to global (bf16); coin-h never leaves
// the block — relu(h+qcoin) -> LDS (reusing the staging buffer) -> amps + z0.
// ---------------------------------------------------------------------------
__global__ __launch_bounds__(256)
void gemm_fused(const float* __restrict__ sent,
                const unsigned short* __restrict__ wswz,
                const float* __restrict__ qcoin,
                const float* __restrict__ coin_w2,
                const float* __restrict__ coin_b2,
                unsigned short* __restrict__ hpathB,
                float* __restrict__ amps,
                float* __restrict__ z0) {
    __shared__ __align__(16) short als[64 * LDSA_STRIDE];   // 51200 B -> 3 blocks/CU
    const int tid = threadIdx.x;
    const int wave = tid >> 6, lane = tid & 63;
    const int m_lane = lane & 15, quad = lane >> 4;
    const int mt = blockIdx.x;                   // 2048 blocks, one tile each
    const int b = mt >> 7;                       // batch (8192 rows / batch)

    // ---- stage A: 64 rows x 384 fp32 -> bf16 LDS via v_cvt_pk_bf16_f32 ----
    const float* abase = sent + (size_t)mt * 64 * D_SZ;
#pragma unroll
    for (int g = 0; g < 3; g++) {
        float4 v[8];
#pragma unroll
        for (int u = 0; u < 8; u++)
            v[u] = *(const float4*)(abase + (size_t)((g * 8 + u) * 256 + tid) * 4);
#pragma unroll
        for (int u = 0; u < 8; u++) {
            int e4 = (g * 8 + u) * 256 + tid;
            int row = e4 / 96;                   // 96 float4 per row
            int c4  = e4 - row * 96;
            int2 p;
            p.x = (int)pkbf(v[u].x, v[u].y);
            p.y = (int)pkbf(v[u].z, v[u].w);
            *(int2*)&als[row * LDSA_STRIDE + c4 * 4] = p;
        }
    }
    __syncthreads();

    // ---- K-loop ----
    const unsigned short* wbase = wswz + (size_t)wave * 4 * KSTEPS * 512 + lane * 8;
    floatx4 acc[4][4];
#pragma unroll
    for (int rt = 0; rt < 4; rt++)
#pragma unroll
        for (int c = 0; c < 4; c++) acc[rt][c] = (floatx4){0.f, 0.f, 0.f, 0.f};

#pragma unroll
    for (int s = 0; s < KSTEPS; s++) {
        short8 bf[4];
#pragma unroll
        for (int c = 0; c < 4; c++)
            bf[c] = *(const short8*)(wbase + (size_t)(c * KSTEPS + s) * 512);
        short8 af[4];
#pragma unroll
        for (int rt = 0; rt < 4; rt++)
            af[rt] = *(const short8*)&als[(rt * 16 + m_lane) * LDSA_STRIDE + s * 32 + quad * 8];
#pragma unroll
        for (int rt = 0; rt < 4; rt++)
#pragma unroll
            for (int c = 0; c < 4; c++)
                acc[rt][c] = __builtin_amdgcn_mfma_f32_16x16x32_bf16(af[rt], bf[c], acc[rt][c], 0, 0, 0);
    }

    // ---- epilogue A: path waves store blocked bf16 h to global ----
    if (wave >= 2) {
        const int colw = (wave & 1) * 64;
#pragma unroll
        for (int rt = 0; rt < 4; rt++) {
            int mt16 = mt * 4 + rt;
#pragma unroll
            for (int c = 0; c < 4; c++) {
                int col = colw + c * 16 + m_lane;
                int2 p;
                p.x = (int)pkbf(acc[rt][c][0], acc[rt][c][1]);
                p.y = (int)pkbf(acc[rt][c][2], acc[rt][c][3]);
                *(int2*)(hpathB + (size_t)mt16 * 2048 + col * 16 + quad * 4) = p;
            }
        }
    }
    __syncthreads();                             // als K-loop reads all done

    // ---- epilogue B: coin waves -> relu(h + qcoin) into LDS (f32) ----
    float* hs  = (float*)als;                    // 64 x 132 f32 = 33792 B
    float* w2s = hs + 64 * 132;                  // 1024 f32 (ends 37888 <= 51200)
    if (wave < 2) {
        const int colw = wave * 64;
        float qc[4];
#pragma unroll
        for (int c = 0; c < 4; c++)
            qc[c] = qcoin[b * H_SZ + colw + c * 16 + m_lane];
#pragma unroll
        for (int rt = 0; rt < 4; rt++)
#pragma unroll
            for (int c = 0; c < 4; c++) {
                int colj = colw + c * 16 + m_lane;
#pragma unroll
                for (int j = 0; j < 4; j++) {
                    int row = rt * 16 + quad * 4 + j;
                    float hv = acc[rt][c][j] + qc[c];
                    hs[row * 132 + colj] = hv > 0.f ? hv : 0.f;
                }
            }
    }
    for (int i = tid; i < H_SZ * K_SZ; i += 256) w2s[i] = coin_w2[i];
    __syncthreads();

    // ---- epilogue C: amps[m][k] = hs_row @ w2 + b2 ; z0 = amps / 256 ----
    {
        const int r = tid >> 2;                  // 0..63 row in tile
        const int kk = (tid & 3) * 2;            // k pair
        float a0 = coin_b2[kk], a1 = coin_b2[kk + 1];
#pragma unroll 8
        for (int c = 0; c < H_SZ; c++) {
            float hv = hs[r * 132 + c];
            float2 w = *(const float2*)&w2s[c * 8 + kk];
            a0 += hv * w.x; a1 += hv * w.y;
        }
        const size_t m = (size_t)mt * 64 + r;
        const float c0 = 1.0f / 256.0f;          // 1/sqrt(N*K)
        *(float2*)(amps + m * 8 + kk) = make_float2(a0, a1);
        *(float2*)(z0   + m * 8 + kk) = make_float2(a0 * c0, a1 * c0);
    }
}

// ---------------------------------------------------------------------------
// walk step (un-normalized; intermediate norms cancel algebraically):
//   v = z[m] + sum_valid z[nbr]
//   last==0:  out[m] = v * amps[m]
//   last==1:  out[m] = v ; atomically accumulate ssq into norms[b]
// ---------------------------------------------------------------------------
__global__ __launch_bounds__(256)
void walk_step(const float* __restrict__ z,
               const int* __restrict__ neighbors,
               const float* __restrict__ amps,
               float* __restrict__ outz,
               float* __restrict__ norms, int last) {
    const int g = blockIdx.x * 256 + threadIdx.x;    // 262144 threads
    const int m = g >> 1, half = g & 1;
    const int b = m >> 13;
    const size_t nbase = (size_t)b << 13;
    const int off = half * 4;

    float4 v = *(const float4*)(z + (size_t)m * 8 + off);
    int nbr[KN_SZ];
    const int4* nb4 = (const int4*)(neighbors + (size_t)m * KN_SZ);
#pragma unroll
    for (int i = 0; i < 4; i++) *(int4*)&nbr[i * 4] = nb4[i];
#pragma unroll
    for (int i = 0; i < KN_SZ; i++) {
        int nn = nbr[i];
        if (nn >= 0 && nn < N_SZ) {
            float4 gv = *(const float4*)(z + (nbase + nn) * 8 + off);
            v.x += gv.x; v.y += gv.y; v.z += gv.z; v.w += gv.w;
        }
    }
    if (!last) {
        float4 a = *(const float4*)(amps + (size_t)m * 8 + off);
        v.x *= a.x; v.y *= a.y; v.z *= a.z; v.w *= a.w;
        *(float4*)(outz + (size_t)m * 8 + off) = v;
    } else {
        *(float4*)(outz + (size_t)m * 8 + off) = v;
        float ss = v.x * v.x + v.y * v.y + v.z * v.z + v.w * v.w;
#pragma unroll
        for (int o = 32; o > 0; o >>= 1) ss += __shfl_down(ss, o);
        __shared__ float blocksum;
        if (threadIdx.x == 0) blocksum = 0.f;
        __syncthreads();
        if ((threadIdx.x & 63) == 0) atomicAdd(&blocksum, ss);
        __syncthreads();
        if (threadIdx.x == 0) atomicAdd(&norms[b], blocksum);
    }
}

// ---------------------------------------------------------------------------
// logits[m] = relu(hpath[m] + qpath[b] + state @ w1_state) @ path_w2 + path_b2
// state = u2[m] * rsqrt(norms[b])  (final normalize, guarded)
// ---------------------------------------------------------------------------
__global__ __launch_bounds__(256)
void logits_kernel(const unsigned short* __restrict__ hpathB,
                   const float* __restrict__ qpath,
                   const float* __restrict__ u2,
                   const float* __restrict__ norms,
                   const float* __restrict__ path_w1,
                   const float* __restrict__ path_w2,
                   const float* __restrict__ path_b2,
                   float* __restrict__ out) {
    __shared__ float w1t[H_SZ * K_SZ];   // w1t[h*8+j] = path_w1[(384+j)*128 + h]
    __shared__ float w2s[H_SZ];
    __shared__ float qps[H_SZ];
    const int tid = threadIdx.x;
    const int m = blockIdx.x * 256 + tid;
    const int b = (blockIdx.x * 256) >> 13;      // block-uniform
    for (int i = tid; i < K_SZ * H_SZ; i += 256) {
        int h = i >> 3, j = i & 7;
        w1t[i] = path_w1[(D_SZ + j) * H_SZ + h];
    }
    if (tid < H_SZ) { w2s[tid] = path_w2[tid]; qps[tid] = qpath[b * H_SZ + tid]; }
    __syncthreads();

    float ssq = norms[b];
    float inv = ssq > 0.f ? rsqrtf(ssq) : 1.0f;
    float st[K_SZ];
    {
        float4 s0 = *(const float4*)(u2 + (size_t)m * 8);
        float4 s1 = *(const float4*)(u2 + (size_t)m * 8 + 4);
        st[0] = s0.x * inv; st[1] = s0.y * inv; st[2] = s0.z * inv; st[3] = s0.w * inv;
        st[4] = s1.x * inv; st[5] = s1.y * inv; st[6] = s1.z * inv; st[7] = s1.w * inv;
    }

    const unsigned short* hb = hpathB + (size_t)(m >> 4) * 2048 + (m & 15);
    float acc = path_b2[0];
    for (int h = 0; h < H_SZ; h++) {
        float hv = bf2f(hb[h * 16]) + qps[h];
        float4 wa = *(const float4*)&w1t[h * 8];
        float4 wb = *(const float4*)&w1t[h * 8 + 4];
        hv += st[0]*wa.x + st[1]*wa.y + st[2]*wa.z + st[3]*wa.w
            + st[4]*wb.x + st[5]*wb.y + st[6]*wb.z + st[7]*wb.w;
        hv = hv > 0.f ? hv : 0.f;
        acc += hv * w2s[h];
    }
    out[m] = acc;
}

// ---------------------------------------------------------------------------
extern "C" void kernel_launch(void* const* d_in, const int* in_sizes, int n_in,
                              void* d_out, int out_size, void* d_ws, size_t ws_size,
                              hipStream_t stream) {
    const float* sent      = (const float*)d_in[0];
    const float* q_embs    = (const float*)d_in[1];
    const int*   neighbors = (const int*)d_in[2];
    const float* coin_w1   = (const float*)d_in[3];
    const float* coin_b1   = (const float*)d_in[4];
    const float* coin_w2   = (const float*)d_in[5];
    const float* coin_b2   = (const float*)d_in[6];
    const float* path_w1   = (const float*)d_in[7];
    const float* path_b1   = (const float*)d_in[8];
    const float* path_w2   = (const float*)d_in[9];
    const float* path_b2   = (const float*)d_in[10];
    float* out = (float*)d_out;

    char* ws = (char*)d_ws;
    unsigned short* wswz = (unsigned short*)ws;                   // 196608 B
    float* qcoin = (float*)(ws + 196608);                         // 8192 B
    float* qpath = (float*)(ws + 204800);                         // 8192 B
    float* norms = (float*)(ws + 212992);                         // 256 B
    unsigned short* hpathB = (unsigned short*)(ws + 213248);      // 33554432 B
    float* amps = (float*)(ws + 33767680);                        // 4 MB
    float* zA   = (float*)(ws + 37961984);                        // 4 MB
    float* zB   = (float*)(ws + 42156288);                        // 4 MB

    prep_kernel<<<401, 256, 0, stream>>>(q_embs, coin_w1, coin_b1, path_w1, path_b1,
                                         wswz, qcoin, qpath, norms);
    gemm_fused<<<MT64, 256, 0, stream>>>(sent, wswz, qcoin, coin_w2, coin_b2,
                                         hpathB, amps, zA);
    walk_step<<<2 * M_TOTAL / 256, 256, 0, stream>>>(zA, neighbors, amps, zB, norms, 0);
    walk_step<<<2 * M_TOTAL / 256, 256, 0, stream>>>(zB, neighbors, amps, zA, norms, 0);
    walk_step<<<2 * M_TOTAL / 256, 256, 0, stream>>>(zA, neighbors, amps, zB, norms, 1);
    logits_kernel<<<M_TOTAL / 256, 256, 0, stream>>>(hpathB, qpath, zB, norms,
                                                     path_w1, path_w2, path_b2, out);
}